// Round 14
// baseline (242.575 us; speedup 1.0000x reference)
//
#include <hip/hip_runtime.h>

#define R_BINS 50
#define NFEAT 7
#define HSZ (R_BINS * NFEAT)   // 350
#define STW 264                // u16 per row; 528B stride

typedef __attribute__((ext_vector_type(8))) short short8;   // 8 bf16
typedef __attribute__((ext_vector_type(4))) float f32x4;

// Forced VOP3P packed ops: value-in/value-out asm, no memory semantics.
__device__ __forceinline__ unsigned pksub(unsigned a, unsigned b) {
    unsigned d;
    asm("v_pk_sub_u16 %0, %1, %2" : "=v"(d) : "v"(a), "v"(b));
    return d;
}
// complement one-hot: halfword -> bf16 2.0 iff NOT zero
__device__ __forceinline__ unsigned ohc(unsigned d, unsigned onepk) {
    unsigned m;
    asm("v_pk_min_u16 %0, %1, %2" : "=v"(m) : "v"(d), "v"(onepk));
    return m << 14;   // 0x4000 = bf16 2.0 where no match
}

struct Quad { float4 p0, p1, p2, v0, v1, v2, m; };

// NOTE: second arg raised 4 -> 8. At (256,4) the attribute capped residency at
// 4 waves/SIMD (measured OccupancyPercent ~47% with every other limit at 8+).
__global__ __launch_bounds__(256, 8) void disk_hist_kernel(
    const float* __restrict__ pos,
    const float* __restrict__ vel,
    const float* __restrict__ mass,
    float* __restrict__ ghist,
    int n)
{
    // ping-pong staging: rows 0..6 bf16 feats, row 7 zeros, row 8 bins u16
    __shared__ __align__(16) unsigned short st16[2][9][STW];
    __shared__ float mg[4][HSZ];

    const int tid  = threadIdx.x;
    const int lane = tid & 63;
    const int w    = tid >> 6;
    const int col  = lane & 15;
    const int g    = lane >> 4;

    for (int i = tid; i < STW; i += 256) { st16[0][7][i] = 0; st16[1][7][i] = 0; }
    __syncthreads();

    f32x4 acc[4] = {{0,0,0,0},{0,0,0,0},{0,0,0,0},{0,0,0,0}};
    f32x4 accT   = {0,0,0,0};                       // sum with A = all-2.0

    union { unsigned u[4]; short8 v; } Acst;        // constant all-2.0 A fragment
    Acst.u[0] = Acst.u[1] = Acst.u[2] = Acst.u[3] = 0x40004000u;

    unsigned onepk = 0x00010001u;
    asm("" : "+v"(onepk));                          // keep in VGPR

    const int brow = (col < NFEAT) ? col : 7;
    const int co   = (w << 6) + (g << 3);
    const unsigned short* pB0 = &st16[0][brow][co];
    const unsigned short* pB1 = &st16[1][brow][co];
    const unsigned short* pN0 = &st16[0][8][co];
    const unsigned short* pN1 = &st16[1][8][co];
    const unsigned cpk0 = (unsigned)col * 0x00010001u;
    const unsigned cpk1 = cpk0 + 0x00100010u;
    const unsigned cpk2 = cpk0 + 0x00200020u;
    const unsigned cpk3 = cpk0 + 0x00300030u;

    const int stride = gridDim.x * blockDim.x;    // 524288
    const int gtid   = blockIdx.x * blockDim.x + tid;
    const int nquads = n >> 2;
    const int niter  = (nquads + stride - 1) / stride;

    const float4* pos4  = (const float4*)pos;
    const float4* vel4  = (const float4*)vel;
    const float4* mass4 = (const float4*)mass;

    #define LOADQ(DST, Q) do {                                                 \
        (DST).p0 = pos4[3*(Q)+0]; (DST).p1 = pos4[3*(Q)+1];                    \
        (DST).p2 = pos4[3*(Q)+2];                                              \
        (DST).v0 = vel4[3*(Q)+0]; (DST).v1 = vel4[3*(Q)+1];                    \
        (DST).v2 = vel4[3*(Q)+2]; (DST).m = mass4[(Q)];                        \
    } while (0)

    // lean producer: guarded rsq, truncated bf16 (1 shr each), no bin clamp
    // (bins 50..127 cancel exactly in the complement merge)
    #define STAGE(U, X, Y, VX, VY, VZ, M, VALID) do {                          \
        float x_=(X), y_=(Y), vx_=(VX), vy_=(VY), vz_=(VZ);                    \
        float d_  = x_*x_ + y_*y_;                                             \
        float ir_ = (d_ > 0.0f) ? __builtin_amdgcn_rsqf(d_) : 0.0f;            \
        float r5_ = d_ * ir_ * 5.0f;            /* = r/DR */                   \
        unsigned bu_ = (unsigned)r5_;                                          \
        float wg_ = (VALID) ? (M) : 0.0f;                                      \
        float vr_ = (x_*vx_ + y_*vy_) * ir_;                                   \
        float vp_ = (y_*vx_ - x_*vy_) * ir_;                                   \
        float f1_ = wg_*vr_, f2_ = f1_*vr_;                                    \
        float f3_ = wg_*vp_, f4_ = f3_*vp_;                                    \
        float f5_ = wg_*vz_, f6_ = f5_*vz_;                                    \
        unsigned short* sb_ = &st16[U][0][tid];                                \
        sb_[0*STW] = (unsigned short)(__builtin_bit_cast(unsigned, wg_) >> 16);\
        sb_[1*STW] = (unsigned short)(__builtin_bit_cast(unsigned, f1_) >> 16);\
        sb_[2*STW] = (unsigned short)(__builtin_bit_cast(unsigned, f2_) >> 16);\
        sb_[3*STW] = (unsigned short)(__builtin_bit_cast(unsigned, f3_) >> 16);\
        sb_[4*STW] = (unsigned short)(__builtin_bit_cast(unsigned, f4_) >> 16);\
        sb_[5*STW] = (unsigned short)(__builtin_bit_cast(unsigned, f5_) >> 16);\
        sb_[6*STW] = (unsigned short)(__builtin_bit_cast(unsigned, f6_) >> 16);\
        sb_[8*STW] = (unsigned short)bu_;                                      \
    } while (0)

    #define BATCH(Braw, Nraw) do {                                             \
        short8 Bv = __builtin_bit_cast(short8, Braw);                          \
        union { unsigned u[4]; short8 v; } A;                                  \
        A.u[0]=ohc(pksub(Nraw.x,cpk0),onepk); A.u[1]=ohc(pksub(Nraw.y,cpk0),onepk); \
        A.u[2]=ohc(pksub(Nraw.z,cpk0),onepk); A.u[3]=ohc(pksub(Nraw.w,cpk0),onepk); \
        acc[0] = __builtin_amdgcn_mfma_f32_16x16x32_bf16(A.v, Bv, acc[0],0,0,0);\
        A.u[0]=ohc(pksub(Nraw.x,cpk1),onepk); A.u[1]=ohc(pksub(Nraw.y,cpk1),onepk); \
        A.u[2]=ohc(pksub(Nraw.z,cpk1),onepk); A.u[3]=ohc(pksub(Nraw.w,cpk1),onepk); \
        acc[1] = __builtin_amdgcn_mfma_f32_16x16x32_bf16(A.v, Bv, acc[1],0,0,0);\
        A.u[0]=ohc(pksub(Nraw.x,cpk2),onepk); A.u[1]=ohc(pksub(Nraw.y,cpk2),onepk); \
        A.u[2]=ohc(pksub(Nraw.z,cpk2),onepk); A.u[3]=ohc(pksub(Nraw.w,cpk2),onepk); \
        acc[2] = __builtin_amdgcn_mfma_f32_16x16x32_bf16(A.v, Bv, acc[2],0,0,0);\
        A.u[0]=ohc(pksub(Nraw.x,cpk3),onepk); A.u[1]=ohc(pksub(Nraw.y,cpk3),onepk); \
        A.u[2]=ohc(pksub(Nraw.z,cpk3),onepk); A.u[3]=ohc(pksub(Nraw.w,cpk3),onepk); \
        acc[3] = __builtin_amdgcn_mfma_f32_16x16x32_bf16(A.v, Bv, acc[3],0,0,0);\
        accT   = __builtin_amdgcn_mfma_f32_16x16x32_bf16(Acst.v, Bv, accT,0,0,0);\
    } while (0)

    #define CONSUME0() do {                                                    \
        uint4 Br0_ = *(const uint4*)pB0;  uint4 Nr0_ = *(const uint4*)pN0;     \
        uint4 Br1_ = *(const uint4*)(pB0+32); uint4 Nr1_ = *(const uint4*)(pN0+32); \
        BATCH(Br0_, Nr0_); BATCH(Br1_, Nr1_);                                  \
    } while (0)
    #define CONSUME1() do {                                                    \
        uint4 Br0_ = *(const uint4*)pB1;  uint4 Nr0_ = *(const uint4*)pN1;     \
        uint4 Br1_ = *(const uint4*)(pB1+32); uint4 Nr1_ = *(const uint4*)(pN1+32); \
        BATCH(Br0_, Nr0_); BATCH(Br1_, Nr1_);                                  \
    } while (0)

    // ---------- prologue ----------
    Quad c, nx;
    LOADQ(c, gtid);                 // gtid < nquads always (stride >> blocks)
    bool cvalid = true;
    STAGE(0, c.p0.x, c.p0.y, c.v0.x, c.v0.y, c.v0.z, c.m.x, cvalid);

    for (int it = 0; it < niter; ++it) {
        int qn_raw = (it + 1) * stride + gtid;
        bool nvalid = qn_raw < nquads;
        int qn = nvalid ? qn_raw : (nquads - 1);
        LOADQ(nx, qn);

        STAGE(1, c.p0.w, c.p1.x, c.v0.w, c.v1.x, c.v1.y, c.m.y, cvalid);
        CONSUME0();                          // staged one full phase ago
        STAGE(0, c.p1.z, c.p1.w, c.v1.z, c.v1.w, c.v2.x, c.m.z, cvalid);
        CONSUME1();
        STAGE(1, c.p2.y, c.p2.z, c.v2.y, c.v2.z, c.v2.w, c.m.w, cvalid);
        CONSUME0();
        c = nx; cvalid = nvalid;
        STAGE(0, c.p0.x, c.p0.y, c.v0.x, c.v0.y, c.v0.z, c.m.x, cvalid);
        CONSUME1();
    }

    // ---- per-wave D tiles -> LDS; hist = (accT - compl)/2 ----
    if (col < NFEAT) {
        #pragma unroll
        for (int t = 0; t < 4; ++t) {
            #pragma unroll
            for (int r = 0; r < 4; ++r) {
                int bin = 16*t + 4*g + r;    // D: col=lane&15, row=(lane>>4)*4+r
                if (bin < R_BINS)
                    mg[w][bin * NFEAT + col] = (accT[r] - acc[t][r]) * 0.5f;
            }
        }
    }
    __syncthreads();

    for (int i = tid; i < HSZ; i += blockDim.x) {
        float s = mg[0][i] + mg[1][i] + mg[2][i] + mg[3][i];
        atomicAdd(ghist + i, s);
    }

    // ---- exact scalar tail (n % 4), block 0 (empty for N=16M) ----
    if (blockIdx.x == 0 && tid < (n & 3)) {
        int p = ((n >> 2) << 2) + tid;
        float x = pos[3*p], y = pos[3*p + 1];
        float r = sqrtf(x*x + y*y);
        int bin = (int)floorf(r * 5.0f);
        if (bin >= 0 && bin < R_BINS && r > 0.0f) {
            float invr = 1.0f / r;
            float vxs = vel[3*p], vys = vel[3*p+1], vzs = vel[3*p+2];
            float vr = (x*vxs + y*vys) * invr;
            float vp = (y*vxs - x*vys) * invr;
            float wg = mass[p];
            float* bptr = ghist + bin * NFEAT;
            atomicAdd(bptr + 0, wg);
            atomicAdd(bptr + 1, wg * vr);
            atomicAdd(bptr + 2, wg * vr * vr);
            atomicAdd(bptr + 3, wg * vp);
            atomicAdd(bptr + 4, wg * vp * vp);
            atomicAdd(bptr + 5, wg * vzs);
            atomicAdd(bptr + 6, wg * vzs * vzs);
        }
    }
}

__global__ void disk_finalize_kernel(const float* __restrict__ gh,
                                     float* __restrict__ out)
{
    int b = threadIdx.x;
    if (b >= R_BINS) return;
    const float* s = gh + b * NFEAT;
    float inv  = 1.0f / s[0];
    float vr_m = s[1] * inv, vr2 = s[2] * inv;
    float vp_m = s[3] * inv, vp2 = s[4] * inv;
    float vz_m = s[5] * inv, vz2 = s[6] * inv;
    out[0 * R_BINS + b] = vp_m;
    out[1 * R_BINS + b] = sqrtf(vp2 - vp_m * vp_m);
    out[2 * R_BINS + b] = vr_m;
    out[3 * R_BINS + b] = sqrtf(vr2 - vr_m * vr_m);
    out[4 * R_BINS + b] = vz_m;
    out[5 * R_BINS + b] = sqrtf(vz2 - vz_m * vz_m);
}

extern "C" void kernel_launch(void* const* d_in, const int* in_sizes, int n_in,
                              void* d_out, int out_size, void* d_ws, size_t ws_size,
                              hipStream_t stream)
{
    const float* pos  = (const float*)d_in[0];
    const float* vel  = (const float*)d_in[1];
    const float* mass = (const float*)d_in[2];
    float* out   = (float*)d_out;
    float* ghist = (float*)d_ws;
    int n = in_sizes[2];   // masses: one per particle

    hipMemsetAsync(ghist, 0, HSZ * sizeof(float), stream);

    disk_hist_kernel<<<2048, 256, 0, stream>>>(pos, vel, mass, ghist, n);
    disk_finalize_kernel<<<1, 64, 0, stream>>>(ghist, out);
}

// Round 16
// 109.719 us; speedup vs baseline: 2.2109x; 2.2109x over previous
//
#include <hip/hip_runtime.h>

#define R_BINS 50
#define NFEAT 7
#define HSZ (R_BINS * NFEAT)   // 350
#define STW 264                // u16 per row; 528B stride

typedef __attribute__((ext_vector_type(8))) short short8;   // 8 bf16
typedef __attribute__((ext_vector_type(4))) float f32x4;

// Forced VOP3P packed ops: value-in/value-out asm, no memory semantics.
__device__ __forceinline__ unsigned pksub(unsigned a, unsigned b) {
    unsigned d;
    asm("v_pk_sub_u16 %0, %1, %2" : "=v"(d) : "v"(a), "v"(b));
    return d;
}
// complement one-hot: halfword -> bf16 2.0 iff NOT zero
__device__ __forceinline__ unsigned ohc(unsigned d, unsigned onepk) {
    unsigned m;
    asm("v_pk_min_u16 %0, %1, %2" : "=v"(m) : "v"(d), "v"(onepk));
    return m << 14;   // 0x4000 = bf16 2.0 where no match
}

struct Quad { float4 p0, p1, p2, v0, v1, v2, m; };

// waves_per_eu(4,4): CLOSED range. launch_bounds(256,4) gave [4,max] and the
// scheduler minimized liveness toward max occupancy (VGPR=48, chunk loads sunk
// to use -> full HBM latency exposed per chunk). LDS caps us at 4 waves/EU
// anyway, so pin min==max and let the allocator keep prefetched loads live.
__global__ __launch_bounds__(256)
__attribute__((amdgpu_waves_per_eu(4, 4)))
void disk_hist_kernel(
    const float* __restrict__ pos,
    const float* __restrict__ vel,
    const float* __restrict__ mass,
    float* __restrict__ ghist,
    int n)
{
    // ping-pong staging: rows 0..6 bf16 feats, row 7 zeros, row 8 bins u16
    __shared__ __align__(16) unsigned short st16[2][9][STW];
    __shared__ float mg[4][HSZ];

    const int tid  = threadIdx.x;
    const int lane = tid & 63;
    const int w    = tid >> 6;
    const int col  = lane & 15;
    const int g    = lane >> 4;

    for (int i = tid; i < STW; i += 256) { st16[0][7][i] = 0; st16[1][7][i] = 0; }
    __syncthreads();

    f32x4 acc[4] = {{0,0,0,0},{0,0,0,0},{0,0,0,0},{0,0,0,0}};
    f32x4 accT   = {0,0,0,0};                       // sum with A = all-2.0

    union { unsigned u[4]; short8 v; } Acst;        // constant all-2.0 A fragment
    Acst.u[0] = Acst.u[1] = Acst.u[2] = Acst.u[3] = 0x40004000u;

    unsigned onepk = 0x00010001u;
    asm("" : "+v"(onepk));                          // keep in VGPR

    const int brow = (col < NFEAT) ? col : 7;
    const int co   = (w << 6) + (g << 3);
    const unsigned short* pB0 = &st16[0][brow][co];
    const unsigned short* pB1 = &st16[1][brow][co];
    const unsigned short* pN0 = &st16[0][8][co];
    const unsigned short* pN1 = &st16[1][8][co];
    const unsigned cpk0 = (unsigned)col * 0x00010001u;
    const unsigned cpk1 = cpk0 + 0x00100010u;
    const unsigned cpk2 = cpk0 + 0x00200020u;
    const unsigned cpk3 = cpk0 + 0x00300030u;

    const int stride = gridDim.x * blockDim.x;    // 524288
    const int gtid   = blockIdx.x * blockDim.x + tid;
    const int nquads = n >> 2;
    const int niter  = (nquads + stride - 1) / stride;

    const float4* pos4  = (const float4*)pos;
    const float4* vel4  = (const float4*)vel;
    const float4* mass4 = (const float4*)mass;

    #define LOADQ(DST, Q) do {                                                 \
        (DST).p0 = pos4[3*(Q)+0]; (DST).p1 = pos4[3*(Q)+1];                    \
        (DST).p2 = pos4[3*(Q)+2];                                              \
        (DST).v0 = vel4[3*(Q)+0]; (DST).v1 = vel4[3*(Q)+1];                    \
        (DST).v2 = vel4[3*(Q)+2]; (DST).m = mass4[(Q)];                        \
    } while (0)

    // lean producer: guarded rsq, truncated bf16 (1 shr each), no bin clamp
    // (bins 50..127 cancel exactly in the complement merge)
    #define STAGE(U, X, Y, VX, VY, VZ, M, VALID) do {                          \
        float x_=(X), y_=(Y), vx_=(VX), vy_=(VY), vz_=(VZ);                    \
        float d_  = x_*x_ + y_*y_;                                             \
        float ir_ = (d_ > 0.0f) ? __builtin_amdgcn_rsqf(d_) : 0.0f;            \
        float r5_ = d_ * ir_ * 5.0f;            /* = r/DR */                   \
        unsigned bu_ = (unsigned)r5_;                                          \
        float wg_ = (VALID) ? (M) : 0.0f;                                      \
        float vr_ = (x_*vx_ + y_*vy_) * ir_;                                   \
        float vp_ = (y_*vx_ - x_*vy_) * ir_;                                   \
        float f1_ = wg_*vr_, f2_ = f1_*vr_;                                    \
        float f3_ = wg_*vp_, f4_ = f3_*vp_;                                    \
        float f5_ = wg_*vz_, f6_ = f5_*vz_;                                    \
        unsigned short* sb_ = &st16[U][0][tid];                                \
        sb_[0*STW] = (unsigned short)(__builtin_bit_cast(unsigned, wg_) >> 16);\
        sb_[1*STW] = (unsigned short)(__builtin_bit_cast(unsigned, f1_) >> 16);\
        sb_[2*STW] = (unsigned short)(__builtin_bit_cast(unsigned, f2_) >> 16);\
        sb_[3*STW] = (unsigned short)(__builtin_bit_cast(unsigned, f3_) >> 16);\
        sb_[4*STW] = (unsigned short)(__builtin_bit_cast(unsigned, f4_) >> 16);\
        sb_[5*STW] = (unsigned short)(__builtin_bit_cast(unsigned, f5_) >> 16);\
        sb_[6*STW] = (unsigned short)(__builtin_bit_cast(unsigned, f6_) >> 16);\
        sb_[8*STW] = (unsigned short)bu_;                                      \
    } while (0)

    #define BATCH(Braw, Nraw) do {                                             \
        short8 Bv = __builtin_bit_cast(short8, Braw);                          \
        union { unsigned u[4]; short8 v; } A;                                  \
        A.u[0]=ohc(pksub(Nraw.x,cpk0),onepk); A.u[1]=ohc(pksub(Nraw.y,cpk0),onepk); \
        A.u[2]=ohc(pksub(Nraw.z,cpk0),onepk); A.u[3]=ohc(pksub(Nraw.w,cpk0),onepk); \
        acc[0] = __builtin_amdgcn_mfma_f32_16x16x32_bf16(A.v, Bv, acc[0],0,0,0);\
        A.u[0]=ohc(pksub(Nraw.x,cpk1),onepk); A.u[1]=ohc(pksub(Nraw.y,cpk1),onepk); \
        A.u[2]=ohc(pksub(Nraw.z,cpk1),onepk); A.u[3]=ohc(pksub(Nraw.w,cpk1),onepk); \
        acc[1] = __builtin_amdgcn_mfma_f32_16x16x32_bf16(A.v, Bv, acc[1],0,0,0);\
        A.u[0]=ohc(pksub(Nraw.x,cpk2),onepk); A.u[1]=ohc(pksub(Nraw.y,cpk2),onepk); \
        A.u[2]=ohc(pksub(Nraw.z,cpk2),onepk); A.u[3]=ohc(pksub(Nraw.w,cpk2),onepk); \
        acc[2] = __builtin_amdgcn_mfma_f32_16x16x32_bf16(A.v, Bv, acc[2],0,0,0);\
        A.u[0]=ohc(pksub(Nraw.x,cpk3),onepk); A.u[1]=ohc(pksub(Nraw.y,cpk3),onepk); \
        A.u[2]=ohc(pksub(Nraw.z,cpk3),onepk); A.u[3]=ohc(pksub(Nraw.w,cpk3),onepk); \
        acc[3] = __builtin_amdgcn_mfma_f32_16x16x32_bf16(A.v, Bv, acc[3],0,0,0);\
        accT   = __builtin_amdgcn_mfma_f32_16x16x32_bf16(Acst.v, Bv, accT,0,0,0);\
    } while (0)

    #define CONSUME0() do {                                                    \
        uint4 Br0_ = *(const uint4*)pB0;  uint4 Nr0_ = *(const uint4*)pN0;     \
        uint4 Br1_ = *(const uint4*)(pB0+32); uint4 Nr1_ = *(const uint4*)(pN0+32); \
        BATCH(Br0_, Nr0_); BATCH(Br1_, Nr1_);                                  \
    } while (0)
    #define CONSUME1() do {                                                    \
        uint4 Br0_ = *(const uint4*)pB1;  uint4 Nr0_ = *(const uint4*)pN1;     \
        uint4 Br1_ = *(const uint4*)(pB1+32); uint4 Nr1_ = *(const uint4*)(pN1+32); \
        BATCH(Br0_, Nr0_); BATCH(Br1_, Nr1_);                                  \
    } while (0)

    // ---------- prologue ----------
    Quad c, nx;
    LOADQ(c, gtid);                 // gtid < nquads always (stride >> blocks)
    bool cvalid = true;
    STAGE(0, c.p0.x, c.p0.y, c.v0.x, c.v0.y, c.v0.z, c.m.x, cvalid);

    for (int it = 0; it < niter; ++it) {
        int qn_raw = (it + 1) * stride + gtid;
        bool nvalid = qn_raw < nquads;
        int qn = nvalid ? qn_raw : (nquads - 1);
        LOADQ(nx, qn);

        STAGE(1, c.p0.w, c.p1.x, c.v0.w, c.v1.x, c.v1.y, c.m.y, cvalid);
        CONSUME0();                          // staged one full phase ago
        STAGE(0, c.p1.z, c.p1.w, c.v1.z, c.v1.w, c.v2.x, c.m.z, cvalid);
        CONSUME1();
        STAGE(1, c.p2.y, c.p2.z, c.v2.y, c.v2.z, c.v2.w, c.m.w, cvalid);
        CONSUME0();
        c = nx; cvalid = nvalid;
        STAGE(0, c.p0.x, c.p0.y, c.v0.x, c.v0.y, c.v0.z, c.m.x, cvalid);
        CONSUME1();
    }

    // ---- per-wave D tiles -> LDS; hist = (accT - compl)/2 ----
    if (col < NFEAT) {
        #pragma unroll
        for (int t = 0; t < 4; ++t) {
            #pragma unroll
            for (int r = 0; r < 4; ++r) {
                int bin = 16*t + 4*g + r;    // D: col=lane&15, row=(lane>>4)*4+r
                if (bin < R_BINS)
                    mg[w][bin * NFEAT + col] = (accT[r] - acc[t][r]) * 0.5f;
            }
        }
    }
    __syncthreads();

    for (int i = tid; i < HSZ; i += blockDim.x) {
        float s = mg[0][i] + mg[1][i] + mg[2][i] + mg[3][i];
        atomicAdd(ghist + i, s);
    }

    // ---- exact scalar tail (n % 4), block 0 (empty for N=16M) ----
    if (blockIdx.x == 0 && tid < (n & 3)) {
        int p = ((n >> 2) << 2) + tid;
        float x = pos[3*p], y = pos[3*p + 1];
        float r = sqrtf(x*x + y*y);
        int bin = (int)floorf(r * 5.0f);
        if (bin >= 0 && bin < R_BINS && r > 0.0f) {
            float invr = 1.0f / r;
            float vxs = vel[3*p], vys = vel[3*p+1], vzs = vel[3*p+2];
            float vr = (x*vxs + y*vys) * invr;
            float vp = (y*vxs - x*vys) * invr;
            float wg = mass[p];
            float* bptr = ghist + bin * NFEAT;
            atomicAdd(bptr + 0, wg);
            atomicAdd(bptr + 1, wg * vr);
            atomicAdd(bptr + 2, wg * vr * vr);
            atomicAdd(bptr + 3, wg * vp);
            atomicAdd(bptr + 4, wg * vp * vp);
            atomicAdd(bptr + 5, wg * vzs);
            atomicAdd(bptr + 6, wg * vzs * vzs);
        }
    }
}

__global__ void disk_finalize_kernel(const float* __restrict__ gh,
                                     float* __restrict__ out)
{
    int b = threadIdx.x;
    if (b >= R_BINS) return;
    const float* s = gh + b * NFEAT;
    float inv  = 1.0f / s[0];
    float vr_m = s[1] * inv, vr2 = s[2] * inv;
    float vp_m = s[3] * inv, vp2 = s[4] * inv;
    float vz_m = s[5] * inv, vz2 = s[6] * inv;
    out[0 * R_BINS + b] = vp_m;
    out[1 * R_BINS + b] = sqrtf(vp2 - vp_m * vp_m);
    out[2 * R_BINS + b] = vr_m;
    out[3 * R_BINS + b] = sqrtf(vr2 - vr_m * vr_m);
    out[4 * R_BINS + b] = vz_m;
    out[5 * R_BINS + b] = sqrtf(vz2 - vz_m * vz_m);
}

extern "C" void kernel_launch(void* const* d_in, const int* in_sizes, int n_in,
                              void* d_out, int out_size, void* d_ws, size_t ws_size,
                              hipStream_t stream)
{
    const float* pos  = (const float*)d_in[0];
    const float* vel  = (const float*)d_in[1];
    const float* mass = (const float*)d_in[2];
    float* out   = (float*)d_out;
    float* ghist = (float*)d_ws;
    int n = in_sizes[2];   // masses: one per particle

    hipMemsetAsync(ghist, 0, HSZ * sizeof(float), stream);

    disk_hist_kernel<<<2048, 256, 0, stream>>>(pos, vel, mass, ghist, n);
    disk_finalize_kernel<<<1, 64, 0, stream>>>(ghist, out);
}

// Round 17
// 109.576 us; speedup vs baseline: 2.2138x; 1.0013x over previous
//
#include <hip/hip_runtime.h>

#define R_BINS 50
#define NFEAT 7
#define HSZ (R_BINS * NFEAT)   // 350
#define STW 264                // u16 per row; 528B stride

typedef __attribute__((ext_vector_type(8))) short short8;   // 8 bf16
typedef __attribute__((ext_vector_type(4))) float f32x4;

// Forced VOP3P packed ops: value-in/value-out asm, no memory semantics.
__device__ __forceinline__ unsigned pksub(unsigned a, unsigned b) {
    unsigned d;
    asm("v_pk_sub_u16 %0, %1, %2" : "=v"(d) : "v"(a), "v"(b));
    return d;
}
// complement one-hot: halfword -> bf16 2.0 iff NOT zero
__device__ __forceinline__ unsigned ohc(unsigned d, unsigned onepk) {
    unsigned m;
    asm("v_pk_min_u16 %0, %1, %2" : "=v"(m) : "v"(d), "v"(onepk));
    return m << 14;   // 0x4000 = bf16 2.0 where no match
}

// zero-cost keep-alive: requires VALUE to be materialized here (load complete),
// emits nothing. Input-only asm — no reordering lies, no clobbers. (rule #17)
#define PIN(X) asm volatile("" :: "v"(X))

struct Quad { float4 p0, p1, p2, v0, v1, v2, m; };

__global__ __launch_bounds__(256, 4) void disk_hist_kernel(
    const float* __restrict__ pos,
    const float* __restrict__ vel,
    const float* __restrict__ mass,
    float* __restrict__ ghist,
    int n)
{
    // ping-pong staging: rows 0..6 bf16 feats, row 7 zeros, row 8 bins u16
    __shared__ __align__(16) unsigned short st16[2][9][STW];
    __shared__ float mg[4][HSZ];

    const int tid  = threadIdx.x;
    const int lane = tid & 63;
    const int w    = tid >> 6;
    const int col  = lane & 15;
    const int g    = lane >> 4;

    for (int i = tid; i < STW; i += 256) { st16[0][7][i] = 0; st16[1][7][i] = 0; }
    __syncthreads();

    f32x4 acc[4] = {{0,0,0,0},{0,0,0,0},{0,0,0,0},{0,0,0,0}};
    f32x4 accT   = {0,0,0,0};                       // sum with A = all-2.0

    union { unsigned u[4]; short8 v; } Acst;        // constant all-2.0 A fragment
    Acst.u[0] = Acst.u[1] = Acst.u[2] = Acst.u[3] = 0x40004000u;

    unsigned onepk = 0x00010001u;
    asm("" : "+v"(onepk));                          // keep in VGPR

    const int brow = (col < NFEAT) ? col : 7;
    const int co   = (w << 6) + (g << 3);
    const unsigned short* pB0 = &st16[0][brow][co];
    const unsigned short* pB1 = &st16[1][brow][co];
    const unsigned short* pN0 = &st16[0][8][co];
    const unsigned short* pN1 = &st16[1][8][co];
    const unsigned cpk0 = (unsigned)col * 0x00010001u;
    const unsigned cpk1 = cpk0 + 0x00100010u;
    const unsigned cpk2 = cpk0 + 0x00200020u;
    const unsigned cpk3 = cpk0 + 0x00300030u;

    const int stride = gridDim.x * blockDim.x;    // 524288
    const int gtid   = blockIdx.x * blockDim.x + tid;
    const int nquads = n >> 2;
    const int niter  = (nquads + stride - 1) / stride;

    const float4* pos4  = (const float4*)pos;
    const float4* vel4  = (const float4*)vel;
    const float4* mass4 = (const float4*)mass;

    #define LOADQ(DST, Q) do {                                                 \
        (DST).p0 = pos4[3*(Q)+0]; (DST).p1 = pos4[3*(Q)+1];                    \
        (DST).p2 = pos4[3*(Q)+2];                                              \
        (DST).v0 = vel4[3*(Q)+0]; (DST).v1 = vel4[3*(Q)+1];                    \
        (DST).v2 = vel4[3*(Q)+2]; (DST).m = mass4[(Q)];                        \
    } while (0)

    // lean producer: guarded rsq, truncated bf16 (1 shr each), no bin clamp
    // (bins 50..127 cancel exactly in the complement merge)
    #define STAGE(U, X, Y, VX, VY, VZ, M, VALID) do {                          \
        float x_=(X), y_=(Y), vx_=(VX), vy_=(VY), vz_=(VZ);                    \
        float d_  = x_*x_ + y_*y_;                                             \
        float ir_ = (d_ > 0.0f) ? __builtin_amdgcn_rsqf(d_) : 0.0f;            \
        float r5_ = d_ * ir_ * 5.0f;            /* = r/DR */                   \
        unsigned bu_ = (unsigned)r5_;                                          \
        float wg_ = (VALID) ? (M) : 0.0f;                                      \
        float vr_ = (x_*vx_ + y_*vy_) * ir_;                                   \
        float vp_ = (y_*vx_ - x_*vy_) * ir_;                                   \
        float f1_ = wg_*vr_, f2_ = f1_*vr_;                                    \
        float f3_ = wg_*vp_, f4_ = f3_*vp_;                                    \
        float f5_ = wg_*vz_, f6_ = f5_*vz_;                                    \
        unsigned short* sb_ = &st16[U][0][tid];                                \
        sb_[0*STW] = (unsigned short)(__builtin_bit_cast(unsigned, wg_) >> 16);\
        sb_[1*STW] = (unsigned short)(__builtin_bit_cast(unsigned, f1_) >> 16);\
        sb_[2*STW] = (unsigned short)(__builtin_bit_cast(unsigned, f2_) >> 16);\
        sb_[3*STW] = (unsigned short)(__builtin_bit_cast(unsigned, f3_) >> 16);\
        sb_[4*STW] = (unsigned short)(__builtin_bit_cast(unsigned, f4_) >> 16);\
        sb_[5*STW] = (unsigned short)(__builtin_bit_cast(unsigned, f5_) >> 16);\
        sb_[6*STW] = (unsigned short)(__builtin_bit_cast(unsigned, f6_) >> 16);\
        sb_[8*STW] = (unsigned short)bu_;                                      \
    } while (0)

    #define BATCH(Braw, Nraw) do {                                             \
        short8 Bv = __builtin_bit_cast(short8, Braw);                          \
        union { unsigned u[4]; short8 v; } A;                                  \
        A.u[0]=ohc(pksub(Nraw.x,cpk0),onepk); A.u[1]=ohc(pksub(Nraw.y,cpk0),onepk); \
        A.u[2]=ohc(pksub(Nraw.z,cpk0),onepk); A.u[3]=ohc(pksub(Nraw.w,cpk0),onepk); \
        acc[0] = __builtin_amdgcn_mfma_f32_16x16x32_bf16(A.v, Bv, acc[0],0,0,0);\
        A.u[0]=ohc(pksub(Nraw.x,cpk1),onepk); A.u[1]=ohc(pksub(Nraw.y,cpk1),onepk); \
        A.u[2]=ohc(pksub(Nraw.z,cpk1),onepk); A.u[3]=ohc(pksub(Nraw.w,cpk1),onepk); \
        acc[1] = __builtin_amdgcn_mfma_f32_16x16x32_bf16(A.v, Bv, acc[1],0,0,0);\
        A.u[0]=ohc(pksub(Nraw.x,cpk2),onepk); A.u[1]=ohc(pksub(Nraw.y,cpk2),onepk); \
        A.u[2]=ohc(pksub(Nraw.z,cpk2),onepk); A.u[3]=ohc(pksub(Nraw.w,cpk2),onepk); \
        acc[2] = __builtin_amdgcn_mfma_f32_16x16x32_bf16(A.v, Bv, acc[2],0,0,0);\
        A.u[0]=ohc(pksub(Nraw.x,cpk3),onepk); A.u[1]=ohc(pksub(Nraw.y,cpk3),onepk); \
        A.u[2]=ohc(pksub(Nraw.z,cpk3),onepk); A.u[3]=ohc(pksub(Nraw.w,cpk3),onepk); \
        acc[3] = __builtin_amdgcn_mfma_f32_16x16x32_bf16(A.v, Bv, acc[3],0,0,0);\
        accT   = __builtin_amdgcn_mfma_f32_16x16x32_bf16(Acst.v, Bv, accT,0,0,0);\
    } while (0)

    #define CONSUME0() do {                                                    \
        uint4 Br0_ = *(const uint4*)pB0;  uint4 Nr0_ = *(const uint4*)pN0;     \
        uint4 Br1_ = *(const uint4*)(pB0+32); uint4 Nr1_ = *(const uint4*)(pN0+32); \
        BATCH(Br0_, Nr0_); BATCH(Br1_, Nr1_);                                  \
    } while (0)
    #define CONSUME1() do {                                                    \
        uint4 Br0_ = *(const uint4*)pB1;  uint4 Nr0_ = *(const uint4*)pN1;     \
        uint4 Br1_ = *(const uint4*)(pB1+32); uint4 Nr1_ = *(const uint4*)(pN1+32); \
        BATCH(Br0_, Nr0_); BATCH(Br1_, Nr1_);                                  \
    } while (0)

    // ---------- prologue ----------
    Quad c, nx;
    LOADQ(c, gtid);                 // gtid < nquads always (stride >> blocks)
    bool cvalid = true;
    STAGE(0, c.p0.x, c.p0.y, c.v0.x, c.v0.y, c.v0.z, c.m.x, cvalid);

    for (int it = 0; it < niter; ++it) {
        int qn_raw = (it + 1) * stride + gtid;
        bool nvalid = qn_raw < nquads;
        int qn = nvalid ? qn_raw : (nquads - 1);
        LOADQ(nx, qn);

        STAGE(1, c.p0.w, c.p1.x, c.v0.w, c.v1.x, c.v1.y, c.m.y, cvalid);
        CONSUME0();                          // staged one full phase ago
        PIN(nx.p0.x); PIN(nx.v0.x);          // p0,v0 must be loaded by here
        STAGE(0, c.p1.z, c.p1.w, c.v1.z, c.v1.w, c.v2.x, c.m.z, cvalid);
        CONSUME1();
        PIN(nx.p1.x); PIN(nx.v1.x); PIN(nx.m.x);
        STAGE(1, c.p2.y, c.p2.z, c.v2.y, c.v2.z, c.v2.w, c.m.w, cvalid);
        CONSUME0();
        PIN(nx.p2.x); PIN(nx.v2.x);
        c = nx; cvalid = nvalid;
        STAGE(0, c.p0.x, c.p0.y, c.v0.x, c.v0.y, c.v0.z, c.m.x, cvalid);
        CONSUME1();
    }

    // ---- per-wave D tiles -> LDS; hist = (accT - compl)/2 ----
    if (col < NFEAT) {
        #pragma unroll
        for (int t = 0; t < 4; ++t) {
            #pragma unroll
            for (int r = 0; r < 4; ++r) {
                int bin = 16*t + 4*g + r;    // D: col=lane&15, row=(lane>>4)*4+r
                if (bin < R_BINS)
                    mg[w][bin * NFEAT + col] = (accT[r] - acc[t][r]) * 0.5f;
            }
        }
    }
    __syncthreads();

    for (int i = tid; i < HSZ; i += blockDim.x) {
        float s = mg[0][i] + mg[1][i] + mg[2][i] + mg[3][i];
        atomicAdd(ghist + i, s);
    }

    // ---- exact scalar tail (n % 4), block 0 (empty for N=16M) ----
    if (blockIdx.x == 0 && tid < (n & 3)) {
        int p = ((n >> 2) << 2) + tid;
        float x = pos[3*p], y = pos[3*p + 1];
        float r = sqrtf(x*x + y*y);
        int bin = (int)floorf(r * 5.0f);
        if (bin >= 0 && bin < R_BINS && r > 0.0f) {
            float invr = 1.0f / r;
            float vxs = vel[3*p], vys = vel[3*p+1], vzs = vel[3*p+2];
            float vr = (x*vxs + y*vys) * invr;
            float vp = (y*vxs - x*vys) * invr;
            float wg = mass[p];
            float* bptr = ghist + bin * NFEAT;
            atomicAdd(bptr + 0, wg);
            atomicAdd(bptr + 1, wg * vr);
            atomicAdd(bptr + 2, wg * vr * vr);
            atomicAdd(bptr + 3, wg * vp);
            atomicAdd(bptr + 4, wg * vp * vp);
            atomicAdd(bptr + 5, wg * vzs);
            atomicAdd(bptr + 6, wg * vzs * vzs);
        }
    }
}

__global__ void disk_finalize_kernel(const float* __restrict__ gh,
                                     float* __restrict__ out)
{
    int b = threadIdx.x;
    if (b >= R_BINS) return;
    const float* s = gh + b * NFEAT;
    float inv  = 1.0f / s[0];
    float vr_m = s[1] * inv, vr2 = s[2] * inv;
    float vp_m = s[3] * inv, vp2 = s[4] * inv;
    float vz_m = s[5] * inv, vz2 = s[6] * inv;
    out[0 * R_BINS + b] = vp_m;
    out[1 * R_BINS + b] = sqrtf(vp2 - vp_m * vp_m);
    out[2 * R_BINS + b] = vr_m;
    out[3 * R_BINS + b] = sqrtf(vr2 - vr_m * vr_m);
    out[4 * R_BINS + b] = vz_m;
    out[5 * R_BINS + b] = sqrtf(vz2 - vz_m * vz_m);
}

extern "C" void kernel_launch(void* const* d_in, const int* in_sizes, int n_in,
                              void* d_out, int out_size, void* d_ws, size_t ws_size,
                              hipStream_t stream)
{
    const float* pos  = (const float*)d_in[0];
    const float* vel  = (const float*)d_in[1];
    const float* mass = (const float*)d_in[2];
    float* out   = (float*)d_out;
    float* ghist = (float*)d_ws;
    int n = in_sizes[2];   // masses: one per particle

    hipMemsetAsync(ghist, 0, HSZ * sizeof(float), stream);

    disk_hist_kernel<<<2048, 256, 0, stream>>>(pos, vel, mass, ghist, n);
    disk_finalize_kernel<<<1, 64, 0, stream>>>(ghist, out);
}